// Round 1
// baseline (882.460 us; speedup 1.0000x reference)
//
#include <hip/hip_runtime.h>

typedef __bf16 bf16x8 __attribute__((ext_vector_type(8)));
typedef float f32x4 __attribute__((ext_vector_type(4)));

// mask position tables: (i,j) offsets within 5x5, and flattened s=i*5+j (for W5 gather)
__constant__ int SL_I[3][9] = {{1,1,1,2,2,2,3,3,3},{0,0,2,4,4,0,0,0,0},{0,0,1,1,2,3,3,4,4}};
__constant__ int SL_J[3][9] = {{1,2,3,1,2,3,1,2,3},{0,4,2,0,4,0,0,0,0},{1,3,0,4,2,0,4,1,3}};
__constant__ int SL_S[3][9] = {{6,7,8,11,12,13,16,17,18},{0,4,12,20,24,0,0,0,0},{1,3,5,9,12,15,19,21,23}};

static __device__ __forceinline__ unsigned short f2b(float f) {
  unsigned int b = __builtin_bit_cast(unsigned int, f);
  b = b + 0x7FFFu + ((b >> 16) & 1u);  // RNE
  return (unsigned short)(b >> 16);
}
static __device__ __forceinline__ float b2f(unsigned short u) {
  unsigned int b = ((unsigned int)u) << 16;
  return __builtin_bit_cast(float, b);
}
static __device__ __forceinline__ float mish_f(float x) {
  float sp = (x > 20.0f) ? x : log1pf(expf(x));
  return x * tanhf(sp);
}

// ---- prep: W5 masked+compressed -> bf16, layout [27][256][576] with kc = u*64 + c ----
__global__ __launch_bounds__(256) void prep_w5_k(const float* __restrict__ W5,
                                                 unsigned short* __restrict__ W5c) {
  int idx = blockIdx.x * 256 + threadIdx.x;      // 27*256*9*64 = 3,981,312
  if (idx >= 27 * 256 * 9 * 64) return;
  int c = idx & 63;
  int t2 = idx >> 6;
  int u = t2 % 9;
  int gm = t2 / 9;                               // gp*256 + m
  int gp = gm >> 8;
  int g = gp / 9;
  int nm = (g == 1) ? 5 : 9;
  if (u >= nm) return;
  int s = SL_S[g][u];
  W5c[idx] = f2b(W5[(size_t)gm * 1600 + c * 25 + s]);
}

__global__ __launch_bounds__(256) void prep_w12_k(const float* __restrict__ W1, const float* __restrict__ W2,
                                                  unsigned short* __restrict__ W1b, unsigned short* __restrict__ W2b) {
  int idx = blockIdx.x * 256 + threadIdx.x;      // 27*256*256 = 1,769,472
  if (idx < 27 * 256 * 256) {
    W1b[idx] = f2b(W1[idx]);
    W2b[idx] = f2b(W2[idx]);
  }
}

__global__ __launch_bounds__(256) void prep_bn_k(const float* __restrict__ b5, const float* __restrict__ gamma,
                                                 const float* __restrict__ beta, const float* __restrict__ rmean,
                                                 const float* __restrict__ rvar,
                                                 float* __restrict__ bn_a, float* __restrict__ bn_c) {
  int i = blockIdx.x * 256 + threadIdx.x;        // 27*256 = 6912
  if (i < 27 * 256) {
    float a = gamma[i] * rsqrtf(rvar[i] + 1e-5f);
    bn_a[i] = a;
    bn_c[i] = (b5[i] - rmean[i]) * a + beta[i];
  }
}

// ---- stage 1: z = patches x W5c^T (compressed K), BN + mish -> H bf16 [27][4096][256] ----
__global__ __launch_bounds__(256) void gemm1_k(const float* __restrict__ X, const unsigned short* __restrict__ W5c,
                                               const float* __restrict__ bn_a, const float* __restrict__ bn_c,
                                               unsigned short* __restrict__ H) {
  __shared__ unsigned short lA[128 * 64];
  __shared__ unsigned short lB[128 * 64];
  const int t = threadIdx.x;
  const int lane = t & 63;
  const int w = t >> 6;
  const int wm = w >> 1, wn = w & 1;
  const int l15 = lane & 15, l4 = lane >> 4;
  const int m0 = blockIdx.x * 128, n0 = blockIdx.y * 128;
  const int gp = blockIdx.z;
  const int g = gp / 9, p = gp - g * 9;
  const int pk = p / 3, pv = p - pk * 3;
  const int nm = (g == 1) ? 5 : 9;

  const f32x4 zero = {0.f, 0.f, 0.f, 0.f};
  f32x4 acc[4][4];
#pragma unroll
  for (int i = 0; i < 4; ++i)
#pragma unroll
    for (int j = 0; j < 4; ++j) acc[i][j] = zero;

  for (int u = 0; u < nm; ++u) {
    const int xoff = (pk + SL_I[g][u]) * 7 + (pv + SL_J[g][u]);
    // A stage: gather x[b, c, pk+i, pv+j] fp32 -> bf16; tile [128 rows][64 c]
    {
      const int c = t & 63;
      const int r0 = t >> 6;
      const float* xp = X + (size_t)(m0 + r0) * 3136 + c * 49 + xoff;
#pragma unroll
      for (int it = 0; it < 32; ++it) {
        float f = xp[it * 4 * 3136];
        lA[(r0 + it * 4) * 64 + c] = f2b(f);
      }
    }
    // B stage: W5c rows n0..n0+127, k-chunk u*64..+64 (bf16, vectorized 16B)
    {
#pragma unroll
      for (int it = 0; it < 4; ++it) {
        int idx = it * 256 + t;
        int row = idx >> 3, ch = idx & 7;
        uint4 v = *(const uint4*)(W5c + (size_t)(gp * 256 + n0 + row) * 576 + u * 64 + ch * 8);
        *(uint4*)(lB + row * 64 + ch * 8) = v;
      }
    }
    __syncthreads();
#pragma unroll
    for (int kk = 0; kk < 2; ++kk) {
      bf16x8 af[4], bfr[4];
#pragma unroll
      for (int f4 = 0; f4 < 4; ++f4)
        af[f4] = *reinterpret_cast<const bf16x8*>(lA + (wm * 64 + f4 * 16 + l15) * 64 + kk * 32 + l4 * 8);
#pragma unroll
      for (int f4 = 0; f4 < 4; ++f4)
        bfr[f4] = *reinterpret_cast<const bf16x8*>(lB + (wn * 64 + f4 * 16 + l15) * 64 + kk * 32 + l4 * 8);
#pragma unroll
      for (int i = 0; i < 4; ++i)
#pragma unroll
        for (int j = 0; j < 4; ++j)
          acc[i][j] = __builtin_amdgcn_mfma_f32_16x16x32_bf16(af[i], bfr[j], acc[i][j], 0, 0, 0);
    }
    __syncthreads();
  }
  // epilogue: BN + mish -> bf16
#pragma unroll
  for (int j = 0; j < 4; ++j) {
    const int col = n0 + wn * 64 + j * 16 + l15;
    const float a = bn_a[gp * 256 + col];
    const float cc = bn_c[gp * 256 + col];
#pragma unroll
    for (int i = 0; i < 4; ++i) {
      const int rbase = m0 + wm * 64 + i * 16 + l4 * 4;
#pragma unroll
      for (int e = 0; e < 4; ++e) {
        float z = acc[i][j][e] * a + cc;
        H[(size_t)(gp * 4096 + rbase + e) * 256 + col] = f2b(mish_f(z));
      }
    }
  }
}

// ---- stages 2/3: C = A x Bw^T (+bias, optional mish) -> bf16 out ----
__global__ __launch_bounds__(256) void gemm23_k(const unsigned short* __restrict__ A, const unsigned short* __restrict__ Bw,
                                                const float* __restrict__ bias, unsigned short* __restrict__ Out,
                                                int act) {
  __shared__ unsigned short lA[128 * 64];
  __shared__ unsigned short lB[128 * 64];
  const int t = threadIdx.x;
  const int lane = t & 63;
  const int w = t >> 6;
  const int wm = w >> 1, wn = w & 1;
  const int l15 = lane & 15, l4 = lane >> 4;
  const int m0 = blockIdx.x * 128, n0 = blockIdx.y * 128;
  const int gp = blockIdx.z;

  const f32x4 zero = {0.f, 0.f, 0.f, 0.f};
  f32x4 acc[4][4];
#pragma unroll
  for (int i = 0; i < 4; ++i)
#pragma unroll
    for (int j = 0; j < 4; ++j) acc[i][j] = zero;

  for (int kt = 0; kt < 4; ++kt) {
#pragma unroll
    for (int it = 0; it < 4; ++it) {
      int idx = it * 256 + t;
      int row = idx >> 3, ch = idx & 7;
      *(uint4*)(lA + row * 64 + ch * 8) =
          *(const uint4*)(A + (size_t)(gp * 4096 + m0 + row) * 256 + kt * 64 + ch * 8);
      *(uint4*)(lB + row * 64 + ch * 8) =
          *(const uint4*)(Bw + (size_t)(gp * 256 + n0 + row) * 256 + kt * 64 + ch * 8);
    }
    __syncthreads();
#pragma unroll
    for (int kk = 0; kk < 2; ++kk) {
      bf16x8 af[4], bfr[4];
#pragma unroll
      for (int f4 = 0; f4 < 4; ++f4)
        af[f4] = *reinterpret_cast<const bf16x8*>(lA + (wm * 64 + f4 * 16 + l15) * 64 + kk * 32 + l4 * 8);
#pragma unroll
      for (int f4 = 0; f4 < 4; ++f4)
        bfr[f4] = *reinterpret_cast<const bf16x8*>(lB + (wn * 64 + f4 * 16 + l15) * 64 + kk * 32 + l4 * 8);
#pragma unroll
      for (int i = 0; i < 4; ++i)
#pragma unroll
        for (int j = 0; j < 4; ++j)
          acc[i][j] = __builtin_amdgcn_mfma_f32_16x16x32_bf16(af[i], bfr[j], acc[i][j], 0, 0, 0);
    }
    __syncthreads();
  }
#pragma unroll
  for (int j = 0; j < 4; ++j) {
    const int col = n0 + wn * 64 + j * 16 + l15;
    const float bi = bias[gp * 256 + col];
#pragma unroll
    for (int i = 0; i < 4; ++i) {
      const int rbase = m0 + wm * 64 + i * 16 + l4 * 4;
#pragma unroll
      for (int e = 0; e < 4; ++e) {
        float z = acc[i][j][e] + bi;
        if (act) z = mish_f(z);
        Out[(size_t)(gp * 4096 + rbase + e) * 256 + col] = f2b(z);
      }
    }
  }
}

// ---- final: copy = sum_{gp<9} o, jump = sum_{gp>=9} o, out = copy*jump ----
__global__ __launch_bounds__(256) void final_k(const unsigned short* __restrict__ O, float* __restrict__ out) {
  int idx = blockIdx.x * 256 + threadIdx.x;  // 4096*256 = 1,048,576
  float cs = 0.f, js = 0.f;
#pragma unroll
  for (int gp = 0; gp < 27; ++gp) {
    float v = b2f(O[(size_t)gp * 1048576 + idx]);
    if (gp < 9) cs += v; else js += v;
  }
  out[idx] = cs * js;
}

extern "C" void kernel_launch(void* const* d_in, const int* in_sizes, int n_in,
                              void* d_out, int out_size, void* d_ws, size_t ws_size,
                              hipStream_t stream) {
  const float* X     = (const float*)d_in[0];
  const float* W5    = (const float*)d_in[1];
  const float* b5    = (const float*)d_in[2];
  const float* gamma = (const float*)d_in[3];
  const float* beta  = (const float*)d_in[4];
  const float* rmean = (const float*)d_in[5];
  const float* rvar  = (const float*)d_in[6];
  const float* W1    = (const float*)d_in[7];
  const float* b1    = (const float*)d_in[8];
  const float* W2    = (const float*)d_in[9];
  const float* b2    = (const float*)d_in[10];
  float* out = (float*)d_out;
  char* ws = (char*)d_ws;

  // ws layout (bytes)
  unsigned short* W5c  = (unsigned short*)(ws);              //  7,962,624
  unsigned short* W1b  = (unsigned short*)(ws + 7962624);    //  3,538,944
  unsigned short* W2b  = (unsigned short*)(ws + 11501568);   //  3,538,944
  float*          bn_a = (float*)(ws + 15040512);            //     27,648
  float*          bn_c = (float*)(ws + 15068160);            //     27,648
  unsigned short* Hbuf = (unsigned short*)(ws + 15095808);   // 56,623,104
  unsigned short* H1b  = (unsigned short*)(ws + 71718912);   // 56,623,104
  unsigned short* Obuf = (unsigned short*)(ws + 128342016);  // 56,623,104  (total ~185 MB)

  prep_w5_k<<<15552, 256, 0, stream>>>(W5, W5c);
  prep_w12_k<<<6912, 256, 0, stream>>>(W1, W2, W1b, W2b);
  prep_bn_k<<<27, 256, 0, stream>>>(b5, gamma, beta, rmean, rvar, bn_a, bn_c);

  gemm1_k<<<dim3(32, 2, 27), 256, 0, stream>>>(X, W5c, bn_a, bn_c, Hbuf);
  gemm23_k<<<dim3(32, 2, 27), 256, 0, stream>>>(Hbuf, W1b, b1, H1b, 1);
  gemm23_k<<<dim3(32, 2, 27), 256, 0, stream>>>(H1b, W2b, b2, Obuf, 0);
  final_k<<<4096, 256, 0, stream>>>(Obuf, out);
}

// Round 2
// 394.923 us; speedup vs baseline: 2.2345x; 2.2345x over previous
//
#include <hip/hip_runtime.h>

typedef __bf16 bf16x8 __attribute__((ext_vector_type(8)));
typedef float f32x4 __attribute__((ext_vector_type(4)));

// mask position tables: (i,j) offsets within 5x5, and flattened s=i*5+j (for W5 gather)
__constant__ int SL_I[3][9] = {{1,1,1,2,2,2,3,3,3},{0,0,2,4,4,0,0,0,0},{0,0,1,1,2,3,3,4,4}};
__constant__ int SL_J[3][9] = {{1,2,3,1,2,3,1,2,3},{0,4,2,0,4,0,0,0,0},{1,3,0,4,2,0,4,1,3}};
__constant__ int SL_S[3][9] = {{6,7,8,11,12,13,16,17,18},{0,4,12,20,24,0,0,0,0},{1,3,5,9,12,15,19,21,23}};

#define GLDS16(gsrc, ldst)                                                        \
  __builtin_amdgcn_global_load_lds(                                               \
      (const __attribute__((address_space(1))) unsigned int*)(gsrc),              \
      (__attribute__((address_space(3))) unsigned int*)(ldst), 16, 0, 0)

static __device__ __forceinline__ unsigned short f2b(float f) {
  unsigned int b = __builtin_bit_cast(unsigned int, f);
  b = b + 0x7FFFu + ((b >> 16) & 1u);  // RNE
  return (unsigned short)(b >> 16);
}
static __device__ __forceinline__ float b2f(unsigned short u) {
  unsigned int b = ((unsigned int)u) << 16;
  return __builtin_bit_cast(float, b);
}
static __device__ __forceinline__ float mish_f(float x) {
  float sp = (x > 20.0f) ? x : log1pf(expf(x));
  return x * tanhf(sp);
}

// ---- prep: X [4096][64][49] f32 -> Xb [49][4096][64] bf16 (s-major, contiguous A tiles) ----
__global__ __launch_bounds__(256) void prep_x_k(const float* __restrict__ X,
                                                unsigned short* __restrict__ Xb) {
  __shared__ float tile[3136];
  const int b = blockIdx.x;
  const float* xp = X + (size_t)b * 3136;
  for (int i = threadIdx.x; i < 3136; i += 256) tile[i] = xp[i];
  __syncthreads();
  for (int i = threadIdx.x; i < 3136; i += 256) {
    int s = i >> 6, c = i & 63;                       // write idx: [s][c]
    Xb[(size_t)s * 262144 + (size_t)b * 64 + c] = f2b(tile[c * 49 + s]);
  }
}

// ---- prep: W5 masked+compressed -> bf16, layout [27][256][576] with kc = u*64 + c ----
__global__ __launch_bounds__(256) void prep_w5_k(const float* __restrict__ W5,
                                                 unsigned short* __restrict__ W5c) {
  int idx = blockIdx.x * 256 + threadIdx.x;      // 27*256*9*64 = 3,981,312
  if (idx >= 27 * 256 * 9 * 64) return;
  int c = idx & 63;
  int t2 = idx >> 6;
  int u = t2 % 9;
  int gm = t2 / 9;                               // gp*256 + m
  int gp = gm >> 8;
  int g = gp / 9;
  int nm = (g == 1) ? 5 : 9;
  if (u >= nm) return;
  int s = SL_S[g][u];
  W5c[idx] = f2b(W5[(size_t)gm * 1600 + c * 25 + s]);
}

__global__ __launch_bounds__(256) void prep_w12_k(const float* __restrict__ W1, const float* __restrict__ W2,
                                                  unsigned short* __restrict__ W1b, unsigned short* __restrict__ W2b) {
  int idx = blockIdx.x * 256 + threadIdx.x;      // 27*256*256 = 1,769,472
  if (idx < 27 * 256 * 256) {
    W1b[idx] = f2b(W1[idx]);
    W2b[idx] = f2b(W2[idx]);
  }
}

__global__ __launch_bounds__(256) void prep_bn_k(const float* __restrict__ b5, const float* __restrict__ gamma,
                                                 const float* __restrict__ beta, const float* __restrict__ rmean,
                                                 const float* __restrict__ rvar,
                                                 float* __restrict__ bn_a, float* __restrict__ bn_c) {
  int i = blockIdx.x * 256 + threadIdx.x;        // 27*256 = 6912
  if (i < 27 * 256) {
    float a = gamma[i] * rsqrtf(rvar[i] + 1e-5f);
    bn_a[i] = a;
    bn_c[i] = (b5[i] - rmean[i]) * a + beta[i];
  }
}

// ---- stage 1: z = Xb x W5c^T (compressed K), BN + mish -> H bf16 [27][4096][256] ----
__global__ __launch_bounds__(256) void gemm1_k(const unsigned short* __restrict__ Xb,
                                               const unsigned short* __restrict__ W5c,
                                               const float* __restrict__ bn_a, const float* __restrict__ bn_c,
                                               unsigned short* __restrict__ H) {
  __shared__ unsigned short lA[128 * 64];
  __shared__ unsigned short lB[128 * 64];
  const int t = threadIdx.x;
  const int lane = t & 63;
  const int w = t >> 6;
  const int wm = w >> 1, wn = w & 1;
  const int l15 = lane & 15, l4 = lane >> 4;
  const int m0 = blockIdx.x * 128, n0 = blockIdx.y * 128;
  const int gp = blockIdx.z;
  const int g = gp / 9, p = gp - g * 9;
  const int pk = p / 3, pv = p - pk * 3;
  const int nm = (g == 1) ? 5 : 9;

  const f32x4 zero = {0.f, 0.f, 0.f, 0.f};
  f32x4 acc[4][4];
#pragma unroll
  for (int i = 0; i < 4; ++i)
#pragma unroll
    for (int j = 0; j < 4; ++j) acc[i][j] = zero;

  for (int u = 0; u < nm; ++u) {
    const int s = (pk + SL_I[g][u]) * 7 + (pv + SL_J[g][u]);
    const unsigned short* srcA = Xb + (size_t)s * 262144 + (size_t)m0 * 64;
#pragma unroll
    for (int it = 0; it < 4; ++it) {
      int idx = it * 256 + t;
      GLDS16(srcA + idx * 8, lA + idx * 8);   // contiguous 16KB tile
    }
#pragma unroll
    for (int it = 0; it < 4; ++it) {
      int idx = it * 256 + t;
      int row = idx >> 3, ch = idx & 7;
      GLDS16(W5c + (size_t)(gp * 256 + n0 + row) * 576 + u * 64 + ch * 8, lB + idx * 8);
    }
    __syncthreads();
#pragma unroll
    for (int kk = 0; kk < 2; ++kk) {
      bf16x8 af[4], bfr[4];
#pragma unroll
      for (int f4 = 0; f4 < 4; ++f4)
        af[f4] = *reinterpret_cast<const bf16x8*>(lA + (wm * 64 + f4 * 16 + l15) * 64 + kk * 32 + l4 * 8);
#pragma unroll
      for (int f4 = 0; f4 < 4; ++f4)
        bfr[f4] = *reinterpret_cast<const bf16x8*>(lB + (wn * 64 + f4 * 16 + l15) * 64 + kk * 32 + l4 * 8);
#pragma unroll
      for (int i = 0; i < 4; ++i)
#pragma unroll
        for (int j = 0; j < 4; ++j)
          acc[i][j] = __builtin_amdgcn_mfma_f32_16x16x32_bf16(af[i], bfr[j], acc[i][j], 0, 0, 0);
    }
    __syncthreads();
  }
  // epilogue: BN + mish -> bf16
#pragma unroll
  for (int j = 0; j < 4; ++j) {
    const int col = n0 + wn * 64 + j * 16 + l15;
    const float a = bn_a[gp * 256 + col];
    const float cc = bn_c[gp * 256 + col];
#pragma unroll
    for (int i = 0; i < 4; ++i) {
      const int rbase = m0 + wm * 64 + i * 16 + l4 * 4;
#pragma unroll
      for (int e = 0; e < 4; ++e) {
        float z = acc[i][j][e] * a + cc;
        H[(size_t)(gp * 4096 + rbase + e) * 256 + col] = f2b(mish_f(z));
      }
    }
  }
}

// ---- stages 2/3: C = A x Bw^T (+bias, optional mish) -> bf16 out ----
__global__ __launch_bounds__(256) void gemm23_k(const unsigned short* __restrict__ A, const unsigned short* __restrict__ Bw,
                                                const float* __restrict__ bias, unsigned short* __restrict__ Out,
                                                int act) {
  __shared__ unsigned short lA[128 * 64];
  __shared__ unsigned short lB[128 * 64];
  const int t = threadIdx.x;
  const int lane = t & 63;
  const int w = t >> 6;
  const int wm = w >> 1, wn = w & 1;
  const int l15 = lane & 15, l4 = lane >> 4;
  const int m0 = blockIdx.x * 128, n0 = blockIdx.y * 128;
  const int gp = blockIdx.z;

  const f32x4 zero = {0.f, 0.f, 0.f, 0.f};
  f32x4 acc[4][4];
#pragma unroll
  for (int i = 0; i < 4; ++i)
#pragma unroll
    for (int j = 0; j < 4; ++j) acc[i][j] = zero;

  for (int kt = 0; kt < 4; ++kt) {
#pragma unroll
    for (int it = 0; it < 4; ++it) {
      int idx = it * 256 + t;
      int row = idx >> 3, ch = idx & 7;
      GLDS16(A + (size_t)(gp * 4096 + m0 + row) * 256 + kt * 64 + ch * 8, lA + idx * 8);
      GLDS16(Bw + (size_t)(gp * 256 + n0 + row) * 256 + kt * 64 + ch * 8, lB + idx * 8);
    }
    __syncthreads();
#pragma unroll
    for (int kk = 0; kk < 2; ++kk) {
      bf16x8 af[4], bfr[4];
#pragma unroll
      for (int f4 = 0; f4 < 4; ++f4)
        af[f4] = *reinterpret_cast<const bf16x8*>(lA + (wm * 64 + f4 * 16 + l15) * 64 + kk * 32 + l4 * 8);
#pragma unroll
      for (int f4 = 0; f4 < 4; ++f4)
        bfr[f4] = *reinterpret_cast<const bf16x8*>(lB + (wn * 64 + f4 * 16 + l15) * 64 + kk * 32 + l4 * 8);
#pragma unroll
      for (int i = 0; i < 4; ++i)
#pragma unroll
        for (int j = 0; j < 4; ++j)
          acc[i][j] = __builtin_amdgcn_mfma_f32_16x16x32_bf16(af[i], bfr[j], acc[i][j], 0, 0, 0);
    }
    __syncthreads();
  }
#pragma unroll
  for (int j = 0; j < 4; ++j) {
    const int col = n0 + wn * 64 + j * 16 + l15;
    const float bi = bias[gp * 256 + col];
#pragma unroll
    for (int i = 0; i < 4; ++i) {
      const int rbase = m0 + wm * 64 + i * 16 + l4 * 4;
#pragma unroll
      for (int e = 0; e < 4; ++e) {
        float z = acc[i][j][e] + bi;
        if (act) z = mish_f(z);
        Out[(size_t)(gp * 4096 + rbase + e) * 256 + col] = f2b(z);
      }
    }
  }
}

// ---- final: copy = sum_{gp<9} o, jump = sum_{gp>=9} o, out = copy*jump (8 elems/thread) ----
__global__ __launch_bounds__(256) void final_k(const unsigned short* __restrict__ O, float* __restrict__ out) {
  const size_t base = ((size_t)blockIdx.x * 256 + threadIdx.x) * 8;  // 131072 threads
  float cs[8], js[8];
#pragma unroll
  for (int e = 0; e < 8; ++e) { cs[e] = 0.f; js[e] = 0.f; }
#pragma unroll
  for (int gp = 0; gp < 27; ++gp) {
    uint4 v = *(const uint4*)(O + (size_t)gp * 1048576 + base);
    const unsigned short* pv = (const unsigned short*)&v;
    if (gp < 9) {
#pragma unroll
      for (int e = 0; e < 8; ++e) cs[e] += b2f(pv[e]);
    } else {
#pragma unroll
      for (int e = 0; e < 8; ++e) js[e] += b2f(pv[e]);
    }
  }
  float4 o0 = {cs[0] * js[0], cs[1] * js[1], cs[2] * js[2], cs[3] * js[3]};
  float4 o1 = {cs[4] * js[4], cs[5] * js[5], cs[6] * js[6], cs[7] * js[7]};
  *(float4*)(out + base) = o0;
  *(float4*)(out + base + 4) = o1;
}

extern "C" void kernel_launch(void* const* d_in, const int* in_sizes, int n_in,
                              void* d_out, int out_size, void* d_ws, size_t ws_size,
                              hipStream_t stream) {
  const float* X     = (const float*)d_in[0];
  const float* W5    = (const float*)d_in[1];
  const float* b5    = (const float*)d_in[2];
  const float* gamma = (const float*)d_in[3];
  const float* beta  = (const float*)d_in[4];
  const float* rmean = (const float*)d_in[5];
  const float* rvar  = (const float*)d_in[6];
  const float* W1    = (const float*)d_in[7];
  const float* b1    = (const float*)d_in[8];
  const float* W2    = (const float*)d_in[9];
  const float* b2    = (const float*)d_in[10];
  float* out = (float*)d_out;
  char* ws = (char*)d_ws;

  // ws layout (bytes), all 16B-aligned
  unsigned short* W5c  = (unsigned short*)(ws);              //  7,962,624
  unsigned short* W1b  = (unsigned short*)(ws + 7962624);    //  3,538,944
  unsigned short* W2b  = (unsigned short*)(ws + 11501568);   //  3,538,944
  float*          bn_a = (float*)(ws + 15040512);            //     27,648
  float*          bn_c = (float*)(ws + 15068160);            //     27,648
  unsigned short* Xb   = (unsigned short*)(ws + 15095808);   // 25,690,112
  unsigned short* Hbuf = (unsigned short*)(ws + 40785920);   // 56,623,104
  unsigned short* H1b  = (unsigned short*)(ws + 97409024);   // 56,623,104
  unsigned short* Obuf = Hbuf;  // gemm3 reads H1b, Hbuf is dead by then -> alias (total ~154 MB)

  prep_x_k<<<4096, 256, 0, stream>>>(X, Xb);
  prep_w5_k<<<15552, 256, 0, stream>>>(W5, W5c);
  prep_w12_k<<<6912, 256, 0, stream>>>(W1, W2, W1b, W2b);
  prep_bn_k<<<27, 256, 0, stream>>>(b5, gamma, beta, rmean, rvar, bn_a, bn_c);

  gemm1_k<<<dim3(32, 2, 27), 256, 0, stream>>>(Xb, W5c, bn_a, bn_c, Hbuf);
  gemm23_k<<<dim3(32, 2, 27), 256, 0, stream>>>(Hbuf, W1b, b1, H1b, 1);
  gemm23_k<<<dim3(32, 2, 27), 256, 0, stream>>>(H1b, W2b, b2, Obuf, 0);
  final_k<<<512, 256, 0, stream>>>(Obuf, out);
}

// Round 3
// 190.931 us; speedup vs baseline: 4.6219x; 2.0684x over previous
//
#include <hip/hip_runtime.h>

typedef __bf16 bf16x8 __attribute__((ext_vector_type(8)));
typedef float f32x4 __attribute__((ext_vector_type(4)));

// mask position tables: (i,j) offsets within 5x5, and flattened s=i*5+j (for W5 gather)
__constant__ int SL_I[3][9] = {{1,1,1,2,2,2,3,3,3},{0,0,2,4,4,0,0,0,0},{0,0,1,1,2,3,3,4,4}};
__constant__ int SL_J[3][9] = {{1,2,3,1,2,3,1,2,3},{0,4,2,0,4,0,0,0,0},{1,3,0,4,2,0,4,1,3}};
__constant__ int SL_S[3][9] = {{6,7,8,11,12,13,16,17,18},{0,4,12,20,24,0,0,0,0},{1,3,5,9,12,15,19,21,23}};

#define GLDS16(gsrc, ldst)                                                        \
  __builtin_amdgcn_global_load_lds(                                               \
      (const __attribute__((address_space(1))) unsigned int*)(gsrc),              \
      (__attribute__((address_space(3))) unsigned int*)(ldst), 16, 0, 0)

static __device__ __forceinline__ unsigned short f2b(float f) {
  return __builtin_bit_cast(unsigned short, (__bf16)f);   // native cvt, RNE
}
static __device__ __forceinline__ float b2f(unsigned short u) {
  unsigned int b = ((unsigned int)u) << 16;
  return __builtin_bit_cast(float, b);
}
// mish(x) = x*tanh(softplus(x)) = x*w/(w+2), w = u*(u+2), u = e^x  (exact identity)
static __device__ __forceinline__ float mish_f(float x) {
  float u = __expf(x);
  float w = u * (u + 2.0f);
  float r = x * w * __builtin_amdgcn_rcpf(w + 2.0f);
  return (x > 20.0f) ? x : r;
}

// ---- prep: X [4096][64][49] f32 -> Xb [49][4096][64] bf16 (s-major, contiguous A tiles) ----
__global__ __launch_bounds__(256) void prep_x_k(const float* __restrict__ X,
                                                unsigned short* __restrict__ Xb) {
  __shared__ float tile[3136];
  const int b = blockIdx.x;
  const float* xp = X + (size_t)b * 3136;
  for (int i = threadIdx.x; i < 3136; i += 256) tile[i] = xp[i];
  __syncthreads();
  for (int i = threadIdx.x; i < 3136; i += 256) {
    int s = i >> 6, c = i & 63;                       // write idx: [s][c]
    Xb[(size_t)s * 262144 + (size_t)b * 64 + c] = f2b(tile[c * 49 + s]);
  }
}

// ---- prep: W5 masked+compressed -> bf16, layout [27][256][576] with kc = u*64 + c ----
__global__ __launch_bounds__(256) void prep_w5_k(const float* __restrict__ W5,
                                                 unsigned short* __restrict__ W5c) {
  int idx = blockIdx.x * 256 + threadIdx.x;      // 27*256*9*64 = 3,981,312
  if (idx >= 27 * 256 * 9 * 64) return;
  int c = idx & 63;
  int t2 = idx >> 6;
  int u = t2 % 9;
  int gm = t2 / 9;                               // gp*256 + m
  int gp = gm >> 8;
  int g = gp / 9;
  int nm = (g == 1) ? 5 : 9;
  if (u >= nm) return;
  int s = SL_S[g][u];
  W5c[idx] = f2b(W5[(size_t)gm * 1600 + c * 25 + s]);
}

__global__ __launch_bounds__(256) void prep_w12_k(const float* __restrict__ W1, const float* __restrict__ W2,
                                                  unsigned short* __restrict__ W1b, unsigned short* __restrict__ W2b) {
  int idx = blockIdx.x * 256 + threadIdx.x;      // 27*256*256 = 1,769,472
  if (idx < 27 * 256 * 256) {
    W1b[idx] = f2b(W1[idx]);
    W2b[idx] = f2b(W2[idx]);
  }
}

__global__ __launch_bounds__(256) void prep_bn_k(const float* __restrict__ b5, const float* __restrict__ gamma,
                                                 const float* __restrict__ beta, const float* __restrict__ rmean,
                                                 const float* __restrict__ rvar,
                                                 float* __restrict__ bn_a, float* __restrict__ bn_c) {
  int i = blockIdx.x * 256 + threadIdx.x;        // 27*256 = 6912
  if (i < 27 * 256) {
    float a = gamma[i] * rsqrtf(rvar[i] + 1e-5f);
    bn_a[i] = a;
    bn_c[i] = (b5[i] - rmean[i]) * a + beta[i];
  }
}

// ---- stage 1: z = Xb x W5c^T (compressed K), BN + mish -> H bf16 [27][4096][256] ----
__global__ __launch_bounds__(256) void gemm1_k(const unsigned short* __restrict__ Xb,
                                               const unsigned short* __restrict__ W5c,
                                               const float* __restrict__ bn_a, const float* __restrict__ bn_c,
                                               unsigned short* __restrict__ H) {
  __shared__ unsigned short smem[16384];
  unsigned short* lA = smem;          // [128][64]
  unsigned short* lB = smem + 8192;   // [128][64]
  const int t = threadIdx.x;
  const int lane = t & 63;
  const int w = t >> 6;
  const int wm = w >> 1, wn = w & 1;
  const int l15 = lane & 15, l4 = lane >> 4;
  const int m0 = blockIdx.x * 128, n0 = blockIdx.y * 128;
  const int gp = blockIdx.z;
  const int g = gp / 9, p = gp - g * 9;
  const int pk = p / 3, pv = p - pk * 3;
  const int nm = (g == 1) ? 5 : 9;

  const f32x4 zero = {0.f, 0.f, 0.f, 0.f};
  f32x4 acc[4][4];
#pragma unroll
  for (int i = 0; i < 4; ++i)
#pragma unroll
    for (int j = 0; j < 4; ++j) acc[i][j] = zero;

  for (int u = 0; u < nm; ++u) {
    const int s = (pk + SL_I[g][u]) * 7 + (pv + SL_J[g][u]);
    const unsigned short* srcA = Xb + (size_t)s * 262144 + (size_t)m0 * 64;
#pragma unroll
    for (int it = 0; it < 4; ++it) {
      int idx = it * 256 + t;
      GLDS16(srcA + idx * 8, lA + idx * 8);   // contiguous 16KB tile
    }
#pragma unroll
    for (int it = 0; it < 4; ++it) {
      int idx = it * 256 + t;
      int row = idx >> 3, ch = idx & 7;
      GLDS16(W5c + (size_t)(gp * 256 + n0 + row) * 576 + u * 64 + ch * 8, lB + idx * 8);
    }
    __syncthreads();
#pragma unroll
    for (int kk = 0; kk < 2; ++kk) {
      bf16x8 af[4], bfr[4];
#pragma unroll
      for (int f4 = 0; f4 < 4; ++f4)
        af[f4] = *reinterpret_cast<const bf16x8*>(lA + (wm * 64 + f4 * 16 + l15) * 64 + kk * 32 + l4 * 8);
#pragma unroll
      for (int f4 = 0; f4 < 4; ++f4)
        bfr[f4] = *reinterpret_cast<const bf16x8*>(lB + (wn * 64 + f4 * 16 + l15) * 64 + kk * 32 + l4 * 8);
#pragma unroll
      for (int i = 0; i < 4; ++i)
#pragma unroll
        for (int j = 0; j < 4; ++j)
          acc[i][j] = __builtin_amdgcn_mfma_f32_16x16x32_bf16(af[i], bfr[j], acc[i][j], 0, 0, 0);
    }
    __syncthreads();
  }
  // epilogue: BN + mish -> bf16, LDS transpose (XOR-swizzled both sides) -> dwordx4 stores
#pragma unroll
  for (int j = 0; j < 4; ++j) {
    const int col = wn * 64 + j * 16 + l15;   // tile-local col
    const float a  = bn_a[gp * 256 + n0 + col];
    const float cc = bn_c[gp * 256 + n0 + col];
#pragma unroll
    for (int i = 0; i < 4; ++i) {
      const int r0 = wm * 64 + i * 16 + l4 * 4;
#pragma unroll
      for (int e = 0; e < 4; ++e) {
        const int r = r0 + e;
        float z = acc[i][j][e] * a + cc;
        smem[r * 128 + (col ^ ((r & 7) << 3))] = f2b(mish_f(z));
      }
    }
  }
  __syncthreads();
  {
    unsigned short* Hg = H + (size_t)gp * 1048576;
#pragma unroll
    for (int it = 0; it < 8; ++it) {
      int idx = it * 256 + t;
      int row = idx >> 4, seg = idx & 15;
      int c8 = (seg * 8) ^ ((row & 7) << 3);
      uint4 v = *(const uint4*)(smem + row * 128 + c8);
      *(uint4*)(Hg + (size_t)(m0 + row) * 256 + n0 + seg * 8) = v;
    }
  }
}

// ---- stages 2/3: C = A x Bw^T (+bias, optional mish) -> bf16 out ----
__global__ __launch_bounds__(256) void gemm23_k(const unsigned short* __restrict__ A, const unsigned short* __restrict__ Bw,
                                                const float* __restrict__ bias, unsigned short* __restrict__ Out,
                                                int act) {
  __shared__ unsigned short smem[16384];
  unsigned short* lA = smem;
  unsigned short* lB = smem + 8192;
  const int t = threadIdx.x;
  const int lane = t & 63;
  const int w = t >> 6;
  const int wm = w >> 1, wn = w & 1;
  const int l15 = lane & 15, l4 = lane >> 4;
  const int m0 = blockIdx.x * 128, n0 = blockIdx.y * 128;
  const int gp = blockIdx.z;

  const f32x4 zero = {0.f, 0.f, 0.f, 0.f};
  f32x4 acc[4][4];
#pragma unroll
  for (int i = 0; i < 4; ++i)
#pragma unroll
    for (int j = 0; j < 4; ++j) acc[i][j] = zero;

  for (int kt = 0; kt < 4; ++kt) {
#pragma unroll
    for (int it = 0; it < 4; ++it) {
      int idx = it * 256 + t;
      int row = idx >> 3, ch = idx & 7;
      GLDS16(A + (size_t)(gp * 4096 + m0 + row) * 256 + kt * 64 + ch * 8, lA + idx * 8);
      GLDS16(Bw + (size_t)(gp * 256 + n0 + row) * 256 + kt * 64 + ch * 8, lB + idx * 8);
    }
    __syncthreads();
#pragma unroll
    for (int kk = 0; kk < 2; ++kk) {
      bf16x8 af[4], bfr[4];
#pragma unroll
      for (int f4 = 0; f4 < 4; ++f4)
        af[f4] = *reinterpret_cast<const bf16x8*>(lA + (wm * 64 + f4 * 16 + l15) * 64 + kk * 32 + l4 * 8);
#pragma unroll
      for (int f4 = 0; f4 < 4; ++f4)
        bfr[f4] = *reinterpret_cast<const bf16x8*>(lB + (wn * 64 + f4 * 16 + l15) * 64 + kk * 32 + l4 * 8);
#pragma unroll
      for (int i = 0; i < 4; ++i)
#pragma unroll
        for (int j = 0; j < 4; ++j)
          acc[i][j] = __builtin_amdgcn_mfma_f32_16x16x32_bf16(af[i], bfr[j], acc[i][j], 0, 0, 0);
    }
    __syncthreads();
  }
  // epilogue: bias (+mish) -> bf16, LDS transpose -> dwordx4 stores
#pragma unroll
  for (int j = 0; j < 4; ++j) {
    const int col = wn * 64 + j * 16 + l15;
    const float bi = bias[gp * 256 + n0 + col];
#pragma unroll
    for (int i = 0; i < 4; ++i) {
      const int r0 = wm * 64 + i * 16 + l4 * 4;
#pragma unroll
      for (int e = 0; e < 4; ++e) {
        const int r = r0 + e;
        float z = acc[i][j][e] + bi;
        if (act) z = mish_f(z);
        smem[r * 128 + (col ^ ((r & 7) << 3))] = f2b(z);
      }
    }
  }
  __syncthreads();
  {
    unsigned short* Og = Out + (size_t)gp * 1048576;
#pragma unroll
    for (int it = 0; it < 8; ++it) {
      int idx = it * 256 + t;
      int row = idx >> 4, seg = idx & 15;
      int c8 = (seg * 8) ^ ((row & 7) << 3);
      uint4 v = *(const uint4*)(smem + row * 128 + c8);
      *(uint4*)(Og + (size_t)(m0 + row) * 256 + n0 + seg * 8) = v;
    }
  }
}

// ---- final: copy = sum_{gp<9} o, jump = sum_{gp>=9} o, out = copy*jump (8 elems/thread) ----
__global__ __launch_bounds__(256) void final_k(const unsigned short* __restrict__ O, float* __restrict__ out) {
  const size_t base = ((size_t)blockIdx.x * 256 + threadIdx.x) * 8;  // 131072 threads
  float cs[8], js[8];
#pragma unroll
  for (int e = 0; e < 8; ++e) { cs[e] = 0.f; js[e] = 0.f; }
#pragma unroll
  for (int gp = 0; gp < 27; ++gp) {
    uint4 v = *(const uint4*)(O + (size_t)gp * 1048576 + base);
    const unsigned short* pv = (const unsigned short*)&v;
    if (gp < 9) {
#pragma unroll
      for (int e = 0; e < 8; ++e) cs[e] += b2f(pv[e]);
    } else {
#pragma unroll
      for (int e = 0; e < 8; ++e) js[e] += b2f(pv[e]);
    }
  }
  float4 o0 = {cs[0] * js[0], cs[1] * js[1], cs[2] * js[2], cs[3] * js[3]};
  float4 o1 = {cs[4] * js[4], cs[5] * js[5], cs[6] * js[6], cs[7] * js[7]};
  *(float4*)(out + base) = o0;
  *(float4*)(out + base + 4) = o1;
}

extern "C" void kernel_launch(void* const* d_in, const int* in_sizes, int n_in,
                              void* d_out, int out_size, void* d_ws, size_t ws_size,
                              hipStream_t stream) {
  const float* X     = (const float*)d_in[0];
  const float* W5    = (const float*)d_in[1];
  const float* b5    = (const float*)d_in[2];
  const float* gamma = (const float*)d_in[3];
  const float* beta  = (const float*)d_in[4];
  const float* rmean = (const float*)d_in[5];
  const float* rvar  = (const float*)d_in[6];
  const float* W1    = (const float*)d_in[7];
  const float* b1    = (const float*)d_in[8];
  const float* W2    = (const float*)d_in[9];
  const float* b2    = (const float*)d_in[10];
  float* out = (float*)d_out;
  char* ws = (char*)d_ws;

  // ws layout (bytes), all 16B-aligned
  unsigned short* W5c  = (unsigned short*)(ws);              //  7,962,624
  unsigned short* W1b  = (unsigned short*)(ws + 7962624);    //  3,538,944
  unsigned short* W2b  = (unsigned short*)(ws + 11501568);   //  3,538,944
  float*          bn_a = (float*)(ws + 15040512);            //     27,648
  float*          bn_c = (float*)(ws + 15068160);            //     27,648
  unsigned short* Xb   = (unsigned short*)(ws + 15095808);   // 25,690,112
  unsigned short* Hbuf = (unsigned short*)(ws + 40785920);   // 56,623,104
  unsigned short* H1b  = (unsigned short*)(ws + 97409024);   // 56,623,104
  unsigned short* Obuf = Hbuf;  // gemm3 reads H1b, Hbuf is dead by then -> alias (total ~154 MB)

  prep_x_k<<<4096, 256, 0, stream>>>(X, Xb);
  prep_w5_k<<<15552, 256, 0, stream>>>(W5, W5c);
  prep_w12_k<<<6912, 256, 0, stream>>>(W1, W2, W1b, W2b);
  prep_bn_k<<<27, 256, 0, stream>>>(b5, gamma, beta, rmean, rvar, bn_a, bn_c);

  gemm1_k<<<dim3(32, 2, 27), 256, 0, stream>>>(Xb, W5c, bn_a, bn_c, Hbuf);
  gemm23_k<<<dim3(32, 2, 27), 256, 0, stream>>>(Hbuf, W1b, b1, H1b, 1);
  gemm23_k<<<dim3(32, 2, 27), 256, 0, stream>>>(H1b, W2b, b2, Obuf, 0);
  final_k<<<512, 256, 0, stream>>>(Obuf, out);
}

// Round 6
// 185.003 us; speedup vs baseline: 4.7700x; 1.0320x over previous
//
#include <hip/hip_runtime.h>

typedef __bf16 bf16x8 __attribute__((ext_vector_type(8)));
typedef float f32x4 __attribute__((ext_vector_type(4)));

// mask position tables: (i,j) offsets within 5x5, and flattened s=i*5+j (for W5 gather)
__constant__ int SL_I[3][9] = {{1,1,1,2,2,2,3,3,3},{0,0,2,4,4,0,0,0,0},{0,0,1,1,2,3,3,4,4}};
__constant__ int SL_J[3][9] = {{1,2,3,1,2,3,1,2,3},{0,4,2,0,4,0,0,0,0},{1,3,0,4,2,0,4,1,3}};
__constant__ int SL_S[3][9] = {{6,7,8,11,12,13,16,17,18},{0,4,12,20,24,0,0,0,0},{1,3,5,9,12,15,19,21,23}};

#define GLDS16(gsrc, ldst)                                                        \
  __builtin_amdgcn_global_load_lds(                                               \
      (const __attribute__((address_space(1))) unsigned int*)(gsrc),              \
      (__attribute__((address_space(3))) unsigned int*)(ldst), 16, 0, 0)

static __device__ __forceinline__ unsigned short f2b(float f) {
  return __builtin_bit_cast(unsigned short, (__bf16)f);   // native cvt, RNE
}
static __device__ __forceinline__ float b2f(unsigned short u) {
  unsigned int b = ((unsigned int)u) << 16;
  return __builtin_bit_cast(float, b);
}
// mish(x) = x*tanh(softplus(x)) = x*w/(w+2), w = u*(u+2), u = e^x  (exact identity)
static __device__ __forceinline__ float mish_f(float x) {
  float u = __expf(x);
  float w = u * (u + 2.0f);
  float r = x * w * __builtin_amdgcn_rcpf(w + 2.0f);
  return (x > 20.0f) ? x : r;
}
// swizzle within a 64-col chunk: group (c>>3) ^= (row&7). Involution.
static __device__ __forceinline__ int swz8(int c, int r) {
  return ((((c >> 3) ^ (r & 7)) << 3) | (c & 7));
}

// ---- prep: X [4096][64][49] f32 -> Xb [49][4096][64] bf16, pre-swizzled ----
__global__ __launch_bounds__(256) void prep_x_k(const float* __restrict__ X,
                                                unsigned short* __restrict__ Xb) {
  __shared__ float tile[3136];
  const int b = blockIdx.x;
  const float* xp = X + (size_t)b * 3136;
  for (int i = threadIdx.x; i < 3136; i += 256) tile[i] = xp[i];
  __syncthreads();
  for (int i = threadIdx.x; i < 3136; i += 256) {
    int s = i >> 6, c = i & 63;
    Xb[(size_t)s * 262144 + (size_t)b * 64 + swz8(c, b)] = f2b(tile[c * 49 + s]);
  }
}

// ---- prep: W5 masked+compressed -> bf16 [27][256][576] (kc = u*64+c), pre-swizzled ----
__global__ __launch_bounds__(256) void prep_w5_k(const float* __restrict__ W5,
                                                 unsigned short* __restrict__ W5c) {
  int idx = blockIdx.x * 256 + threadIdx.x;      // output position; 27*256*9*64
  if (idx >= 27 * 256 * 9 * 64) return;
  int c = idx & 63;
  int t2 = idx >> 6;
  int u = t2 % 9;
  int gm = t2 / 9;                               // gp*256 + m
  int m = gm & 255;
  int g = (gm >> 8) / 9;
  int nm = (g == 1) ? 5 : 9;
  if (u >= nm) return;
  int c_src = swz8(c, m);
  W5c[idx] = f2b(W5[(size_t)gm * 1600 + c_src * 25 + SL_S[g][u]]);
}

__global__ __launch_bounds__(256) void prep_w12_k(const float* __restrict__ W1, const float* __restrict__ W2,
                                                  unsigned short* __restrict__ W1b, unsigned short* __restrict__ W2b) {
  int idx = blockIdx.x * 256 + threadIdx.x;      // 27*256*256
  if (idx < 27 * 256 * 256) {
    int n = (idx >> 8) & 255;
    int c = idx & 63;
    int src = (idx & ~63) | swz8(c, n);
    W1b[idx] = f2b(W1[src]);
    W2b[idx] = f2b(W2[src]);
  }
}

__global__ __launch_bounds__(256) void prep_bn_k(const float* __restrict__ b5, const float* __restrict__ gamma,
                                                 const float* __restrict__ beta, const float* __restrict__ rmean,
                                                 const float* __restrict__ rvar,
                                                 float* __restrict__ bn_a, float* __restrict__ bn_c) {
  int i = blockIdx.x * 256 + threadIdx.x;        // 27*256
  if (i < 27 * 256) {
    float a = gamma[i] * rsqrtf(rvar[i] + 1e-5f);
    bn_a[i] = a;
    bn_c[i] = (b5[i] - rmean[i]) * a + beta[i];
  }
}

// ---- stage 1: z = Xb x W5c^T, BN + mish -> H bf16 [27][4096][256] (H pre-swizzled) ----
__global__ __launch_bounds__(256) void gemm1_k(const unsigned short* __restrict__ Xb,
                                               const unsigned short* __restrict__ W5c,
                                               const float* __restrict__ bn_a, const float* __restrict__ bn_c,
                                               unsigned short* __restrict__ H) {
  __shared__ unsigned short smem[16384];  // lA 8192 + lB 8192 shorts = 32 KB
  unsigned short* lA = smem;
  unsigned short* lB = smem + 8192;
  const int t = threadIdx.x;
  const int lane = t & 63;
  const int w = t >> 6;
  const int wm = w >> 1, wn = w & 1;
  const int l15 = lane & 15, l4 = lane >> 4;
  const int sw = l15 & 7;
  const int m0 = blockIdx.x * 128, n0 = blockIdx.y * 128;
  const int gp = blockIdx.z;
  const int g = gp / 9, p = gp - g * 9;
  const int pk = p / 3, pv = p - pk * 3;
  const int nm = (g == 1) ? 5 : 9;

  const f32x4 zero = {0.f, 0.f, 0.f, 0.f};
  f32x4 acc[4][4];
#pragma unroll
  for (int i = 0; i < 4; ++i)
#pragma unroll
    for (int j = 0; j < 4; ++j) acc[i][j] = zero;

  for (int u = 0; u < nm; ++u) {
    const int s = (pk + SL_I[g][u]) * 7 + (pv + SL_J[g][u]);
    const unsigned short* srcA = Xb + (size_t)s * 262144 + (size_t)m0 * 64;
#pragma unroll
    for (int it = 0; it < 4; ++it) {
      int idx = it * 256 + t;
      GLDS16(srcA + idx * 8, lA + idx * 8);
    }
#pragma unroll
    for (int it = 0; it < 4; ++it) {
      int idx = it * 256 + t;
      int row = idx >> 3, ch = idx & 7;
      GLDS16(W5c + (size_t)(gp * 256 + n0 + row) * 576 + u * 64 + ch * 8, lB + idx * 8);
    }
    __syncthreads();
#pragma unroll
    for (int kk = 0; kk < 2; ++kk) {
      bf16x8 af[4], bfr[4];
#pragma unroll
      for (int f4 = 0; f4 < 4; ++f4)
        af[f4] = *reinterpret_cast<const bf16x8*>(lA + (wm * 64 + f4 * 16 + l15) * 64 + (((kk * 4 + l4) ^ sw) << 3));
#pragma unroll
      for (int f4 = 0; f4 < 4; ++f4)
        bfr[f4] = *reinterpret_cast<const bf16x8*>(lB + (wn * 64 + f4 * 16 + l15) * 64 + (((kk * 4 + l4) ^ sw) << 3));
#pragma unroll
      for (int i = 0; i < 4; ++i)
#pragma unroll
        for (int j = 0; j < 4; ++j)
          acc[i][j] = __builtin_amdgcn_mfma_f32_16x16x32_bf16(af[i], bfr[j], acc[i][j], 0, 0, 0);
    }
    __syncthreads();
  }
  // epilogue: BN + mish -> bf16, LDS transpose -> dwordx4 stores (H stored pre-swizzled)
#pragma unroll
  for (int j = 0; j < 4; ++j) {
    const int col = wn * 64 + j * 16 + l15;
    const float a  = bn_a[gp * 256 + n0 + col];
    const float cc = bn_c[gp * 256 + n0 + col];
#pragma unroll
    for (int i = 0; i < 4; ++i) {
      const int r0 = wm * 64 + i * 16 + l4 * 4;
#pragma unroll
      for (int e = 0; e < 4; ++e) {
        const int r = r0 + e;
        float z = acc[i][j][e] * a + cc;
        smem[r * 128 + (col ^ ((r & 7) << 3))] = f2b(mish_f(z));
      }
    }
  }
  __syncthreads();
  {
    unsigned short* Hg = H + (size_t)gp * 1048576;
#pragma unroll
    for (int it = 0; it < 8; ++it) {
      int idx = it * 256 + t;
      int row = idx >> 4, seg = idx & 15;
      int c8 = (seg * 8) ^ ((row & 7) << 3);
      uint4 v = *(const uint4*)(smem + row * 128 + c8);
      int colout = n0 + (seg >> 3) * 64 + (((seg & 7) ^ (row & 7)) << 3);  // pre-swizzled store
      *(uint4*)(Hg + (size_t)(m0 + row) * 256 + colout) = v;
    }
  }
}

// ---- stages 2/3: C = A x Bw^T (+bias, optional mish); A,Bw pre-swizzled; out swz optional ----
__global__ __launch_bounds__(256) void gemm23_k(const unsigned short* __restrict__ A, const unsigned short* __restrict__ Bw,
                                                const float* __restrict__ bias, unsigned short* __restrict__ Out,
                                                int act, int swz_out) {
  __shared__ unsigned short smem[16384];
  unsigned short* lA = smem;
  unsigned short* lB = smem + 8192;
  const int t = threadIdx.x;
  const int lane = t & 63;
  const int w = t >> 6;
  const int wm = w >> 1, wn = w & 1;
  const int l15 = lane & 15, l4 = lane >> 4;
  const int sw = l15 & 7;
  const int m0 = blockIdx.x * 128, n0 = blockIdx.y * 128;
  const int gp = blockIdx.z;

  const f32x4 zero = {0.f, 0.f, 0.f, 0.f};
  f32x4 acc[4][4];
#pragma unroll
  for (int i = 0; i < 4; ++i)
#pragma unroll
    for (int j = 0; j < 4; ++j) acc[i][j] = zero;

  for (int kt = 0; kt < 4; ++kt) {
#pragma unroll
    for (int it = 0; it < 4; ++it) {
      int idx = it * 256 + t;
      int row = idx >> 3, ch = idx & 7;
      GLDS16(A + (size_t)(gp * 4096 + m0 + row) * 256 + kt * 64 + ch * 8, lA + idx * 8);
      GLDS16(Bw + (size_t)(gp * 256 + n0 + row) * 256 + kt * 64 + ch * 8, lB + idx * 8);
    }
    __syncthreads();
#pragma unroll
    for (int kk = 0; kk < 2; ++kk) {
      bf16x8 af[4], bfr[4];
#pragma unroll
      for (int f4 = 0; f4 < 4; ++f4)
        af[f4] = *reinterpret_cast<const bf16x8*>(lA + (wm * 64 + f4 * 16 + l15) * 64 + (((kk * 4 + l4) ^ sw) << 3));
#pragma unroll
      for (int f4 = 0; f4 < 4; ++f4)
        bfr[f4] = *reinterpret_cast<const bf16x8*>(lB + (wn * 64 + f4 * 16 + l15) * 64 + (((kk * 4 + l4) ^ sw) << 3));
#pragma unroll
      for (int i = 0; i < 4; ++i)
#pragma unroll
        for (int j = 0; j < 4; ++j)
          acc[i][j] = __builtin_amdgcn_mfma_f32_16x16x32_bf16(af[i], bfr[j], acc[i][j], 0, 0, 0);
    }
    __syncthreads();
  }
  // epilogue: bias (+mish) -> bf16, LDS transpose -> dwordx4 stores
#pragma unroll
  for (int j = 0; j < 4; ++j) {
    const int col = wn * 64 + j * 16 + l15;
    const float bi = bias[gp * 256 + n0 + col];
#pragma unroll
    for (int i = 0; i < 4; ++i) {
      const int r0 = wm * 64 + i * 16 + l4 * 4;
#pragma unroll
      for (int e = 0; e < 4; ++e) {
        const int r = r0 + e;
        float z = acc[i][j][e] + bi;
        if (act) z = mish_f(z);
        smem[r * 128 + (col ^ ((r & 7) << 3))] = f2b(z);
      }
    }
  }
  __syncthreads();
  {
    unsigned short* Og = Out + (size_t)gp * 1048576;
#pragma unroll
    for (int it = 0; it < 8; ++it) {
      int idx = it * 256 + t;
      int row = idx >> 4, seg = idx & 15;
      int c8 = (seg * 8) ^ ((row & 7) << 3);
      uint4 v = *(const uint4*)(smem + row * 128 + c8);
      int colout = swz_out ? (seg >> 3) * 64 + (((seg & 7) ^ (row & 7)) << 3) : seg * 8;
      *(uint4*)(Og + (size_t)(m0 + row) * 256 + n0 + colout) = v;
    }
  }
}

// ---- final: copy = sum_{gp<9} o, jump = sum_{gp>=9} o, out = copy*jump ----
__global__ __launch_bounds__(256) void final_k(const unsigned short* __restrict__ O, float* __restrict__ out) {
  const size_t base = ((size_t)blockIdx.x * 256 + threadIdx.x) * 8;
  float cs[8], js[8];
#pragma unroll
  for (int e = 0; e < 8; ++e) { cs[e] = 0.f; js[e] = 0.f; }
#pragma unroll
  for (int gp = 0; gp < 27; ++gp) {
    uint4 v = *(const uint4*)(O + (size_t)gp * 1048576 + base);
    const unsigned short* pv = (const unsigned short*)&v;
    if (gp < 9) {
#pragma unroll
      for (int e = 0; e < 8; ++e) cs[e] += b2f(pv[e]);
    } else {
#pragma unroll
      for (int e = 0; e < 8; ++e) js[e] += b2f(pv[e]);
    }
  }
  float4 o0 = {cs[0] * js[0], cs[1] * js[1], cs[2] * js[2], cs[3] * js[3]};
  float4 o1 = {cs[4] * js[4], cs[5] * js[5], cs[6] * js[6], cs[7] * js[7]};
  *(float4*)(out + base) = o0;
  *(float4*)(out + base + 4) = o1;
}

extern "C" void kernel_launch(void* const* d_in, const int* in_sizes, int n_in,
                              void* d_out, int out_size, void* d_ws, size_t ws_size,
                              hipStream_t stream) {
  const float* X     = (const float*)d_in[0];
  const float* W5    = (const float*)d_in[1];
  const float* b5    = (const float*)d_in[2];
  const float* gamma = (const float*)d_in[3];
  const float* beta  = (const float*)d_in[4];
  const float* rmean = (const float*)d_in[5];
  const float* rvar  = (const float*)d_in[6];
  const float* W1    = (const float*)d_in[7];
  const float* b1    = (const float*)d_in[8];
  const float* W2    = (const float*)d_in[9];
  const float* b2    = (const float*)d_in[10];
  float* out = (float*)d_out;
  char* ws = (char*)d_ws;

  // ws layout (bytes), all 16B-aligned
  unsigned short* W5c  = (unsigned short*)(ws);              //  7,962,624
  unsigned short* W1b  = (unsigned short*)(ws + 7962624);    //  3,538,944
  unsigned short* W2b  = (unsigned short*)(ws + 11501568);   //  3,538,944
  float*          bn_a = (float*)(ws + 15040512);            //     27,648
  float*          bn_c = (float*)(ws + 15068160);            //     27,648
  unsigned short* Xb   = (unsigned short*)(ws + 15095808);   // 25,690,112
  unsigned short* Hbuf = (unsigned short*)(ws + 40785920);   // 56,623,104
  unsigned short* H1b  = (unsigned short*)(ws + 97409024);   // 56,623,104
  unsigned short* Obuf = Hbuf;  // gemm3 reads H1b; Hbuf dead by then -> alias

  prep_x_k<<<4096, 256, 0, stream>>>(X, Xb);
  prep_w5_k<<<15552, 256, 0, stream>>>(W5, W5c);
  prep_w12_k<<<6912, 256, 0, stream>>>(W1, W2, W1b, W2b);
  prep_bn_k<<<27, 256, 0, stream>>>(b5, gamma, beta, rmean, rvar, bn_a, bn_c);

  gemm1_k<<<dim3(32, 2, 27), 256, 0, stream>>>(Xb, W5c, bn_a, bn_c, Hbuf);
  gemm23_k<<<dim3(32, 2, 27), 256, 0, stream>>>(Hbuf, W1b, b1, H1b, 1, 1);
  gemm23_k<<<dim3(32, 2, 27), 256, 0, stream>>>(H1b, W2b, b2, Obuf, 0, 0);
  final_k<<<512, 256, 0, stream>>>(Obuf, out);
}